// Round 3
// baseline (2449.713 us; speedup 1.0000x reference)
//
#include <hip/hip_runtime.h>
#include <hip/hip_bf16.h>

// ---------------- graph prep ----------------

__global__ void count_kernel(const int* __restrict__ col, int* __restrict__ cnt, int E) {
    int e = blockIdx.x * 256 + threadIdx.x;
    if (e < E) atomicAdd(&cnt[col[e]], 1);
}

// single-block exclusive scan of cnt[0..n) -> ptr[0..n]
__global__ void scan_kernel(const int* __restrict__ cnt, int* __restrict__ ptr, int n) {
    __shared__ int sums[1024];
    int t = threadIdx.x;
    int chunk = (n + 1023) / 1024;
    int lo = t * chunk;
    int hi = lo + chunk; if (hi > n) hi = n;
    int s = 0;
    for (int i = lo; i < hi; ++i) s += cnt[i];
    sums[t] = s;
    __syncthreads();
    for (int off = 1; off < 1024; off <<= 1) {
        int v = (t >= off) ? sums[t - off] : 0;
        __syncthreads();
        sums[t] += v;
        __syncthreads();
    }
    int run = (t == 0) ? 0 : sums[t - 1];
    for (int i = lo; i < hi; ++i) { ptr[i] = run; run += cnt[i]; }
    if (lo < n && hi == n) ptr[n] = run;
}

__global__ void dinv_fill_kernel(const int* __restrict__ cnt, const int* __restrict__ ptr,
                                 float* __restrict__ dinv, int* __restrict__ fillp, int n) {
    int i = blockIdx.x * 256 + threadIdx.x;
    if (i >= n) return;
    dinv[i] = rsqrtf((float)(cnt[i] + 1));   // deg includes self-loop, always >=1
    fillp[i] = ptr[i];
}

__global__ void fill_kernel(const int* __restrict__ row, const int* __restrict__ col,
                            int* __restrict__ fillp, int* __restrict__ csr_row, int E) {
    int e = blockIdx.x * 256 + threadIdx.x;
    if (e >= E) return;
    int c = col[e];
    int pos = atomicAdd(&fillp[c], 1);
    csr_row[pos] = row[e];
}

// ---------------- dense GEMM: C[n,FOUT] = A[n,K] @ W[K,FOUT] ----------------

template<int K, int FOUT>
__global__ void gemm_kernel(const float* __restrict__ A, const float* __restrict__ W,
                            float* __restrict__ C, int n) {
    constexpr int ROWS = 64;
    constexpr int RG = 256 / FOUT;      // row groups
    constexpr int RPT = ROWS / RG;      // rows per thread
    __shared__ float As[ROWS * K];
    int t = threadIdx.x;
    int r0 = blockIdx.x * ROWS;
    for (int i = t; i < ROWS * K; i += 256) {
        int r = r0 + i / K;
        As[i] = (r < n) ? A[(size_t)r0 * K + i] : 0.f;
    }
    __syncthreads();
    int j = t % FOUT;
    int rg = t / FOUT;
    int rbase = rg * RPT;
    float acc[RPT];
#pragma unroll
    for (int i = 0; i < RPT; ++i) acc[i] = 0.f;
    for (int k = 0; k < K; ++k) {
        float w = W[k * FOUT + j];
#pragma unroll
        for (int i = 0; i < RPT; ++i)
            acc[i] += As[(rbase + i) * K + k] * w;
    }
#pragma unroll
    for (int i = 0; i < RPT; ++i) {
        int r = r0 + rbase + i;
        if (r < n) C[(size_t)r * FOUT + j] = acc[i];
    }
}

// K=32 -> 1 dot product per node
__global__ void dot32_kernel(const float* __restrict__ A, const float* __restrict__ W,
                             float* __restrict__ out, int n) {
    int i = blockIdx.x * 256 + threadIdx.x;
    if (i >= n) return;
    float acc = 0.f;
#pragma unroll
    for (int k = 0; k < 32; ++k) acc += A[(size_t)i * 32 + k] * W[k];
    out[i] = acc;
}

// ---------------- propagate: out = relu(dinv[v]*(sum_in h*dinv + h[v]*dinv[v]) + b) ----------------

template<int F>
__global__ void prop_kernel(const float* __restrict__ H, const int* __restrict__ ptr,
                            const int* __restrict__ rows, const float* __restrict__ dinv,
                            const float* __restrict__ bias, float* __restrict__ out, int n) {
    constexpr int NPB = 256 / F;
    int t = threadIdx.x;
    int f = t % F;
    int ln = t / F;
    int node = blockIdx.x * NPB + ln;
    if (node >= n) return;
    float dn = dinv[node];
    float acc = H[(size_t)node * F + f] * dn;      // self loop term
    int e0 = ptr[node], e1 = ptr[node + 1];
    for (int e = e0; e < e1; ++e) {
        int r = rows[e];
        acc += H[(size_t)r * F + f] * dinv[r];
    }
    float v = acc * dn + bias[f];
    out[(size_t)node * F + f] = v > 0.f ? v : 0.f;
}

// ---------------- segment softmax + pooling ----------------

__global__ void segmax_kernel(const float* __restrict__ w, const int* __restrict__ batch,
                              float* __restrict__ m, int n) {
    int i = blockIdx.x * 256 + threadIdx.x;
    if (i >= n) return;
    // w >= 0 (post-relu), so int-bit compare == float compare; m pre-zeroed
    atomicMax((int*)&m[batch[i]], __float_as_int(w[i]));
}

__global__ void segexp_kernel(const float* __restrict__ w, const int* __restrict__ batch,
                              const float* __restrict__ m, float* __restrict__ e,
                              float* __restrict__ s, int n) {
    int i = blockIdx.x * 256 + threadIdx.x;
    if (i >= n) return;
    int g = batch[i];
    float ev = expf(w[i] - m[g]);
    e[i] = ev;
    atomicAdd(&s[g], ev);
}

// pooled[g,f] += x[i,f] * e[i]/(s[g]+1e-16); batch sorted -> chunked accumulation
__global__ void pooled_kernel(const float* __restrict__ x, const float* __restrict__ e,
                              const float* __restrict__ s, const int* __restrict__ batch,
                              float* __restrict__ pooled, int n) {
    constexpr int CH = 128;
    int f = threadIdx.x;      // 128 threads
    int n0 = blockIdx.x * CH;
    int nend = n0 + CH; if (nend > n) nend = n;
    if (n0 >= n) return;
    float acc = 0.f;
    int curg = batch[n0];
    for (int i = n0; i < nend; ++i) {
        int g = batch[i];
        if (g != curg) {
            atomicAdd(&pooled[curg * 128 + f], acc);
            acc = 0.f; curg = g;
        }
        float a = e[i] / (s[g] + 1e-16f);
        acc += x[(size_t)i * 128 + f] * a;
    }
    atomicAdd(&pooled[curg * 128 + f], acc);
}

// ---------------- final MLP ----------------

__global__ void mlp1_kernel(const float* __restrict__ pooled, const float* __restrict__ Wm1,
                            const float* __restrict__ bm1, float* __restrict__ hidden) {
    int g = blockIdx.x, j = threadIdx.x;   // 128 threads
    __shared__ float p[128];
    p[j] = pooled[g * 128 + j];
    __syncthreads();
    float acc = bm1[j];
    for (int k = 0; k < 128; ++k) acc += p[k] * Wm1[k * 128 + j];
    hidden[g * 128 + j] = acc > 0.f ? acc : 0.f;
}

__global__ void mlp2_kernel(const float* __restrict__ hidden, const float* __restrict__ Wm2,
                            const float* __restrict__ bm2, float* __restrict__ out) {
    int g = blockIdx.x, j = threadIdx.x;   // 256 threads
    __shared__ float h[128];
    if (j < 128) h[j] = hidden[g * 128 + j];
    __syncthreads();
    float acc = bm2[j];
    for (int k = 0; k < 128; ++k) acc += h[k] * Wm2[k * 256 + j];
    out[g * 256 + j] = acc;
}

// ---------------- launch ----------------

extern "C" void kernel_launch(void* const* d_in, const int* in_sizes, int n_in,
                              void* d_out, int out_size, void* d_ws, size_t ws_size,
                              hipStream_t stream) {
    const float* x    = (const float*)d_in[0];
    const int*   ei   = (const int*)d_in[1];
    const int*   batch= (const int*)d_in[2];
    const float* W1 = (const float*)d_in[3];  const float* b1 = (const float*)d_in[4];
    const float* W2 = (const float*)d_in[5];  const float* b2 = (const float*)d_in[6];
    const float* W3 = (const float*)d_in[7];  const float* b3 = (const float*)d_in[8];
    const float* Wa1= (const float*)d_in[9];  const float* ba1= (const float*)d_in[10];
    const float* Wa2= (const float*)d_in[11]; const float* ba2= (const float*)d_in[12];
    const float* Wa3= (const float*)d_in[13]; const float* ba3= (const float*)d_in[14];
    const float* Wm1= (const float*)d_in[15]; const float* bm1= (const float*)d_in[16];
    const float* Wm2= (const float*)d_in[17]; const float* bm2= (const float*)d_in[18];
    float* out = (float*)d_out;

    const int N = in_sizes[0] / 128;
    const int E = in_sizes[1] / 2;
    const int G = out_size / 256;

    const int* row = ei;        // edge_index[0]
    const int* col = ei + E;    // edge_index[1]

    // workspace layout (256B-aligned chunks)
    char* wp = (char*)d_ws;
    auto alloc = [&](size_t bytes) {
        void* p = wp;
        wp += (bytes + 255) & ~(size_t)255;
        return p;
    };
    int*   cnt     = (int*)alloc((size_t)N * 4);
    int*   ptr     = (int*)alloc((size_t)(N + 1) * 4);
    int*   fillp   = (int*)alloc((size_t)N * 4);
    int*   csr_row = (int*)alloc((size_t)E * 4);
    float* dinv    = (float*)alloc((size_t)N * 4);
    float* bufA    = (float*)alloc((size_t)N * 128 * 4);
    float* bufB    = (float*)alloc((size_t)N * 128 * 4);
    float* wb0     = (float*)alloc((size_t)N * 4);
    float* wb1     = (float*)alloc((size_t)N * 4);
    float* segm    = (float*)alloc((size_t)G * 4);
    float* segs    = (float*)alloc((size_t)G * 4);
    float* pooled  = (float*)alloc((size_t)G * 128 * 4);
    float* hidden  = (float*)alloc((size_t)G * 128 * 4);

    hipMemsetAsync(cnt, 0, (size_t)N * 4, stream);
    hipMemsetAsync(segm, 0, (size_t)G * 4, stream);
    hipMemsetAsync(segs, 0, (size_t)G * 4, stream);
    hipMemsetAsync(pooled, 0, (size_t)G * 128 * 4, stream);

    const int EB = (E + 255) / 256;
    const int NB = (N + 255) / 256;

    count_kernel<<<EB, 256, 0, stream>>>(col, cnt, E);
    scan_kernel<<<1, 1024, 0, stream>>>(cnt, ptr, N);
    dinv_fill_kernel<<<NB, 256, 0, stream>>>(cnt, ptr, dinv, fillp, N);
    fill_kernel<<<EB, 256, 0, stream>>>(row, col, fillp, csr_row, E);

    const int GB64 = (N + 63) / 64;

    // GCN layer 1..3 (128 -> 128)
    gemm_kernel<128,128><<<GB64, 256, 0, stream>>>(x,    W1, bufA, N);
    prop_kernel<128><<<(N + 1) / 2, 256, 0, stream>>>(bufA, ptr, csr_row, dinv, b1, bufB, N);
    gemm_kernel<128,128><<<GB64, 256, 0, stream>>>(bufB, W2, bufA, N);
    prop_kernel<128><<<(N + 1) / 2, 256, 0, stream>>>(bufA, ptr, csr_row, dinv, b2, bufB, N);
    gemm_kernel<128,128><<<GB64, 256, 0, stream>>>(bufB, W3, bufA, N);
    prop_kernel<128><<<(N + 1) / 2, 256, 0, stream>>>(bufA, ptr, csr_row, dinv, b3, bufB, N);
    // bufB = x3 [N,128]

    // attention branch
    float* a64_lin = bufA;                       // [N,64]
    float* a64     = bufA + (size_t)N * 64;      // [N,64]
    gemm_kernel<128,64><<<GB64, 256, 0, stream>>>(bufB, Wa1, a64_lin, N);
    prop_kernel<64><<<(N + 3) / 4, 256, 0, stream>>>(a64_lin, ptr, csr_row, dinv, ba1, a64, N);

    float* a32_lin = bufA;                       // [N,32] (a64_lin dead)
    float* a32     = bufA + (size_t)N * 32;      // [N,32]
    gemm_kernel<64,32><<<GB64, 256, 0, stream>>>(a64, Wa2, a32_lin, N);
    prop_kernel<32><<<(N + 7) / 8, 256, 0, stream>>>(a32_lin, ptr, csr_row, dinv, ba2, a32, N);

    dot32_kernel<<<NB, 256, 0, stream>>>(a32, Wa3, wb0, N);
    prop_kernel<1><<<(N + 255) / 256, 256, 0, stream>>>(wb0, ptr, csr_row, dinv, ba3, wb1, N);

    // segment softmax + attention pooling
    segmax_kernel<<<NB, 256, 0, stream>>>(wb1, batch, segm, N);
    segexp_kernel<<<NB, 256, 0, stream>>>(wb1, batch, segm, wb0, segs, N);
    pooled_kernel<<<(N + 127) / 128, 128, 0, stream>>>(bufB, wb0, segs, batch, pooled, N);

    // final MLP
    mlp1_kernel<<<G, 128, 0, stream>>>(pooled, Wm1, bm1, hidden);
    mlp2_kernel<<<G, 256, 0, stream>>>(hidden, Wm2, bm2, out);
}

// Round 4
// 1586.004 us; speedup vs baseline: 1.5446x; 1.5446x over previous
//
#include <hip/hip_runtime.h>
#include <hip/hip_bf16.h>

struct f4 { float x, y, z, w; };
__device__ __forceinline__ f4 ld4(const float* p) { return *(const f4*)p; }
__device__ __forceinline__ void st4(float* p, f4 v) { *(f4*)p = v; }
__device__ __forceinline__ void acc4(f4& a, f4 b) { a.x += b.x; a.y += b.y; a.z += b.z; a.w += b.w; }

// ---------------- graph prep ----------------

__global__ void count_kernel(const int* __restrict__ col, int* __restrict__ cnt, int E) {
    int e = blockIdx.x * 256 + threadIdx.x;
    if (e < E) atomicAdd(&cnt[col[e]], 1);
}

// single-block exclusive scan of cnt[0..n) -> ptr[0..n]
__global__ void scan_kernel(const int* __restrict__ cnt, int* __restrict__ ptr, int n) {
    __shared__ int sums[1024];
    int t = threadIdx.x;
    int chunk = (n + 1023) / 1024;
    int lo = t * chunk;
    int hi = lo + chunk; if (hi > n) hi = n;
    int s = 0;
    for (int i = lo; i < hi; ++i) s += cnt[i];
    sums[t] = s;
    __syncthreads();
    for (int off = 1; off < 1024; off <<= 1) {
        int v = (t >= off) ? sums[t - off] : 0;
        __syncthreads();
        sums[t] += v;
        __syncthreads();
    }
    int run = (t == 0) ? 0 : sums[t - 1];
    for (int i = lo; i < hi; ++i) { ptr[i] = run; run += cnt[i]; }
    if (lo < n && hi == n) ptr[n] = run;
}

__global__ void dinv_fill_kernel(const int* __restrict__ cnt, const int* __restrict__ ptr,
                                 float* __restrict__ dinv, int* __restrict__ fillp, int n) {
    int i = blockIdx.x * 256 + threadIdx.x;
    if (i >= n) return;
    dinv[i] = rsqrtf((float)(cnt[i] + 1));   // deg includes self-loop, always >=1
    fillp[i] = ptr[i];
}

__global__ void fill_kernel(const int* __restrict__ row, const int* __restrict__ col,
                            int* __restrict__ fillp, int* __restrict__ csr_row, int E) {
    int e = blockIdx.x * 256 + threadIdx.x;
    if (e >= E) return;
    int c = col[e];
    int pos = atomicAdd(&fillp[c], 1);
    csr_row[pos] = row[e];
}

// ---------------- dense GEMM: C[n,FOUT] = (A[n,K] @ W[K,FOUT]) * scale[row] ----------------
// A-tile in LDS (broadcast reads), W streamed from L2. 4-wide k-unroll, float4 accumulators.

template<int K, int FOUT>
__global__ __launch_bounds__(256) void gemm_kernel(const float* __restrict__ A,
                            const float* __restrict__ W, const float* __restrict__ scale,
                            float* __restrict__ C, int n) {
    constexpr int ROWS = 64;
    constexpr int NCG = FOUT / 4;       // column groups (4 cols each)
    constexpr int RG  = 256 / NCG;      // row groups
    constexpr int RPT = ROWS / RG;      // rows per thread
    __shared__ float As[ROWS * K];
    int t = threadIdx.x;
    int r0 = blockIdx.x * ROWS;
    // stage A tile (float4), zero-pad tail rows
    for (int i = t; i < ROWS * K / 4; i += 256) {
        int idx = i * 4;
        int r = r0 + idx / K;
        f4 v;
        if (r < n) v = ld4(A + (size_t)r0 * K + idx);
        else { v.x = v.y = v.z = v.w = 0.f; }
        st4(As + idx, v);
    }
    __syncthreads();
    int cg = t % NCG, rg = t / NCG;
    int c = cg * 4, rb = rg * RPT;
    f4 acc[RPT];
#pragma unroll
    for (int i = 0; i < RPT; ++i) { acc[i].x = acc[i].y = acc[i].z = acc[i].w = 0.f; }
    for (int k = 0; k < K; k += 4) {
        f4 w0 = ld4(W + (size_t)(k + 0) * FOUT + c);
        f4 w1 = ld4(W + (size_t)(k + 1) * FOUT + c);
        f4 w2 = ld4(W + (size_t)(k + 2) * FOUT + c);
        f4 w3 = ld4(W + (size_t)(k + 3) * FOUT + c);
#pragma unroll
        for (int i = 0; i < RPT; ++i) {
            f4 a = ld4(As + (rb + i) * K + k);
            acc[i].x += a.x * w0.x + a.y * w1.x + a.z * w2.x + a.w * w3.x;
            acc[i].y += a.x * w0.y + a.y * w1.y + a.z * w2.y + a.w * w3.y;
            acc[i].z += a.x * w0.z + a.y * w1.z + a.z * w2.z + a.w * w3.z;
            acc[i].w += a.x * w0.w + a.y * w1.w + a.z * w2.w + a.w * w3.w;
        }
    }
#pragma unroll
    for (int i = 0; i < RPT; ++i) {
        int r = r0 + rb + i;
        if (r < n) {
            float s = scale[r];
            f4 v = acc[i];
            v.x *= s; v.y *= s; v.z *= s; v.w *= s;
            st4(C + (size_t)r * FOUT + c, v);
        }
    }
}

// K=32 -> 1 dot product per node, scaled by dinv
__global__ void dot32_kernel(const float* __restrict__ A, const float* __restrict__ W,
                             const float* __restrict__ dinv, float* __restrict__ out, int n) {
    int i = blockIdx.x * 256 + threadIdx.x;
    if (i >= n) return;
    float acc = 0.f;
#pragma unroll
    for (int k = 0; k < 32; k += 4) {
        f4 a = ld4(A + (size_t)i * 32 + k);
        f4 w = ld4(W + k);
        acc += a.x * w.x + a.y * w.y + a.z * w.z + a.w * w.w;
    }
    out[i] = acc * dinv[i];
}

// ---------------- propagate: out[v] = relu(dinv[v]*(sum_in hs[r] + hs[v]) + b) ----------------
// hs is pre-scaled by dinv[row] (GEMM epilogue). 4x-unrolled edge loop, float4 lanes.

template<int F>
__global__ __launch_bounds__(256) void prop_kernel(const float* __restrict__ Hs,
                            const int* __restrict__ ptr, const int* __restrict__ rows,
                            const float* __restrict__ dinv, const float* __restrict__ bias,
                            float* __restrict__ out, int n) {
    constexpr int L = F / 4;            // lanes per node
    constexpr int NPB = 256 / L;        // nodes per block
    int t = threadIdx.x;
    int q = t % L;
    int ln = t / L;
    int node = blockIdx.x * NPB + ln;
    if (node >= n) return;
    const int f4i = q * 4;
    f4 a0 = ld4(Hs + (size_t)node * F + f4i);   // self term (pre-scaled)
    f4 a1, a2, a3;
    a1.x=a1.y=a1.z=a1.w=0.f; a2=a1; a3=a1;
    int e0 = ptr[node], e1 = ptr[node + 1];
    int e = e0;
    for (; e + 4 <= e1; e += 4) {
        int r0 = rows[e], r1 = rows[e+1], r2 = rows[e+2], r3 = rows[e+3];
        acc4(a0, ld4(Hs + (size_t)r0 * F + f4i));
        acc4(a1, ld4(Hs + (size_t)r1 * F + f4i));
        acc4(a2, ld4(Hs + (size_t)r2 * F + f4i));
        acc4(a3, ld4(Hs + (size_t)r3 * F + f4i));
    }
    for (; e < e1; ++e) acc4(a0, ld4(Hs + (size_t)rows[e] * F + f4i));
    acc4(a0, a1); acc4(a2, a3); acc4(a0, a2);
    float dn = dinv[node];
    f4 b = ld4(bias + f4i);
    f4 v;
    v.x = a0.x * dn + b.x; v.y = a0.y * dn + b.y;
    v.z = a0.z * dn + b.z; v.w = a0.w * dn + b.w;
    v.x = v.x > 0.f ? v.x : 0.f; v.y = v.y > 0.f ? v.y : 0.f;
    v.z = v.z > 0.f ? v.z : 0.f; v.w = v.w > 0.f ? v.w : 0.f;
    st4(out + (size_t)node * F + f4i, v);
}

// F=1 variant (scalar weights path)
__global__ void prop1_kernel(const float* __restrict__ Hs, const int* __restrict__ ptr,
                             const int* __restrict__ rows, const float* __restrict__ dinv,
                             const float* __restrict__ bias, float* __restrict__ out, int n) {
    int node = blockIdx.x * 256 + threadIdx.x;
    if (node >= n) return;
    float a0 = Hs[node], a1 = 0.f, a2 = 0.f, a3 = 0.f;
    int e0 = ptr[node], e1 = ptr[node + 1];
    int e = e0;
    for (; e + 4 <= e1; e += 4) {
        a0 += Hs[rows[e]];
        a1 += Hs[rows[e+1]];
        a2 += Hs[rows[e+2]];
        a3 += Hs[rows[e+3]];
    }
    for (; e < e1; ++e) a0 += Hs[rows[e]];
    float v = (a0 + a1 + a2 + a3) * dinv[node] + bias[0];
    out[node] = v > 0.f ? v : 0.f;
}

// ---------------- segment softmax + pooling ----------------

__global__ void segmax_kernel(const float* __restrict__ w, const int* __restrict__ batch,
                              float* __restrict__ m, int n) {
    int i = blockIdx.x * 256 + threadIdx.x;
    if (i >= n) return;
    // w >= 0 (post-relu), so int-bit compare == float compare; m pre-zeroed
    atomicMax((int*)&m[batch[i]], __float_as_int(w[i]));
}

__global__ void segexp_kernel(const float* __restrict__ w, const int* __restrict__ batch,
                              const float* __restrict__ m, float* __restrict__ e,
                              float* __restrict__ s, int n) {
    int i = blockIdx.x * 256 + threadIdx.x;
    if (i >= n) return;
    int g = batch[i];
    float ev = expf(w[i] - m[g]);
    e[i] = ev;
    atomicAdd(&s[g], ev);
}

// pooled[g,f] += x[i,f] * e[i]/(s[g]+1e-16); batch sorted -> chunked accumulation
__global__ void pooled_kernel(const float* __restrict__ x, const float* __restrict__ e,
                              const float* __restrict__ s, const int* __restrict__ batch,
                              float* __restrict__ pooled, int n) {
    constexpr int CH = 128;
    int f = threadIdx.x;      // 128 threads
    int n0 = blockIdx.x * CH;
    int nend = n0 + CH; if (nend > n) nend = n;
    if (n0 >= n) return;
    float acc = 0.f;
    int curg = batch[n0];
    for (int i = n0; i < nend; ++i) {
        int g = batch[i];
        if (g != curg) {
            atomicAdd(&pooled[curg * 128 + f], acc);
            acc = 0.f; curg = g;
        }
        float a = e[i] / (s[g] + 1e-16f);
        acc += x[(size_t)i * 128 + f] * a;
    }
    atomicAdd(&pooled[curg * 128 + f], acc);
}

// ---------------- final MLP ----------------

__global__ void mlp1_kernel(const float* __restrict__ pooled, const float* __restrict__ Wm1,
                            const float* __restrict__ bm1, float* __restrict__ hidden) {
    int g = blockIdx.x, j = threadIdx.x;   // 128 threads
    __shared__ float p[128];
    p[j] = pooled[g * 128 + j];
    __syncthreads();
    float acc = bm1[j];
    for (int k = 0; k < 128; ++k) acc += p[k] * Wm1[k * 128 + j];
    hidden[g * 128 + j] = acc > 0.f ? acc : 0.f;
}

__global__ void mlp2_kernel(const float* __restrict__ hidden, const float* __restrict__ Wm2,
                            const float* __restrict__ bm2, float* __restrict__ out) {
    int g = blockIdx.x, j = threadIdx.x;   // 256 threads
    __shared__ float h[128];
    if (j < 128) h[j] = hidden[g * 128 + j];
    __syncthreads();
    float acc = bm2[j];
    for (int k = 0; k < 128; ++k) acc += h[k] * Wm2[k * 256 + j];
    out[g * 256 + j] = acc;
}

// ---------------- launch ----------------

extern "C" void kernel_launch(void* const* d_in, const int* in_sizes, int n_in,
                              void* d_out, int out_size, void* d_ws, size_t ws_size,
                              hipStream_t stream) {
    const float* x    = (const float*)d_in[0];
    const int*   ei   = (const int*)d_in[1];
    const int*   batch= (const int*)d_in[2];
    const float* W1 = (const float*)d_in[3];  const float* b1 = (const float*)d_in[4];
    const float* W2 = (const float*)d_in[5];  const float* b2 = (const float*)d_in[6];
    const float* W3 = (const float*)d_in[7];  const float* b3 = (const float*)d_in[8];
    const float* Wa1= (const float*)d_in[9];  const float* ba1= (const float*)d_in[10];
    const float* Wa2= (const float*)d_in[11]; const float* ba2= (const float*)d_in[12];
    const float* Wa3= (const float*)d_in[13]; const float* ba3= (const float*)d_in[14];
    const float* Wm1= (const float*)d_in[15]; const float* bm1= (const float*)d_in[16];
    const float* Wm2= (const float*)d_in[17]; const float* bm2= (const float*)d_in[18];
    float* out = (float*)d_out;

    const int N = in_sizes[0] / 128;
    const int E = in_sizes[1] / 2;
    const int G = out_size / 256;

    const int* row = ei;        // edge_index[0]
    const int* col = ei + E;    // edge_index[1]

    // workspace layout (256B-aligned chunks)
    char* wp = (char*)d_ws;
    auto alloc = [&](size_t bytes) {
        void* p = wp;
        wp += (bytes + 255) & ~(size_t)255;
        return p;
    };
    int*   cnt     = (int*)alloc((size_t)N * 4);
    int*   ptr     = (int*)alloc((size_t)(N + 1) * 4);
    int*   fillp   = (int*)alloc((size_t)N * 4);
    int*   csr_row = (int*)alloc((size_t)E * 4);
    float* dinv    = (float*)alloc((size_t)N * 4);
    float* bufA    = (float*)alloc((size_t)N * 128 * 4);
    float* bufB    = (float*)alloc((size_t)N * 128 * 4);
    float* wb0     = (float*)alloc((size_t)N * 4);
    float* wb1     = (float*)alloc((size_t)N * 4);
    float* segm    = (float*)alloc((size_t)G * 4);
    float* segs    = (float*)alloc((size_t)G * 4);
    float* pooled  = (float*)alloc((size_t)G * 128 * 4);
    float* hidden  = (float*)alloc((size_t)G * 128 * 4);

    hipMemsetAsync(cnt, 0, (size_t)N * 4, stream);
    hipMemsetAsync(segm, 0, (size_t)G * 4, stream);
    hipMemsetAsync(segs, 0, (size_t)G * 4, stream);
    hipMemsetAsync(pooled, 0, (size_t)G * 128 * 4, stream);

    const int EB = (E + 255) / 256;
    const int NB = (N + 255) / 256;

    count_kernel<<<EB, 256, 0, stream>>>(col, cnt, E);
    scan_kernel<<<1, 1024, 0, stream>>>(cnt, ptr, N);
    dinv_fill_kernel<<<NB, 256, 0, stream>>>(cnt, ptr, dinv, fillp, N);
    fill_kernel<<<EB, 256, 0, stream>>>(row, col, fillp, csr_row, E);

    const int GB64 = (N + 63) / 64;

    // GCN layer 1..3 (128 -> 128); GEMM writes hs = (A@W)*dinv[row]
    gemm_kernel<128,128><<<GB64, 256, 0, stream>>>(x,    W1, dinv, bufA, N);
    prop_kernel<128><<<(N + 7) / 8, 256, 0, stream>>>(bufA, ptr, csr_row, dinv, b1, bufB, N);
    gemm_kernel<128,128><<<GB64, 256, 0, stream>>>(bufB, W2, dinv, bufA, N);
    prop_kernel<128><<<(N + 7) / 8, 256, 0, stream>>>(bufA, ptr, csr_row, dinv, b2, bufB, N);
    gemm_kernel<128,128><<<GB64, 256, 0, stream>>>(bufB, W3, dinv, bufA, N);
    prop_kernel<128><<<(N + 7) / 8, 256, 0, stream>>>(bufA, ptr, csr_row, dinv, b3, bufB, N);
    // bufB = x3 [N,128]

    // attention branch
    float* a64_lin = bufA;                       // [N,64]
    float* a64     = bufA + (size_t)N * 64;      // [N,64]
    gemm_kernel<128,64><<<GB64, 256, 0, stream>>>(bufB, Wa1, dinv, a64_lin, N);
    prop_kernel<64><<<(N + 15) / 16, 256, 0, stream>>>(a64_lin, ptr, csr_row, dinv, ba1, a64, N);

    float* a32_lin = bufA;                       // [N,32] (a64_lin dead)
    float* a32     = bufA + (size_t)N * 32;      // [N,32]
    gemm_kernel<64,32><<<GB64, 256, 0, stream>>>(a64, Wa2, dinv, a32_lin, N);
    prop_kernel<32><<<(N + 31) / 32, 256, 0, stream>>>(a32_lin, ptr, csr_row, dinv, ba2, a32, N);

    dot32_kernel<<<NB, 256, 0, stream>>>(a32, Wa3, dinv, wb0, N);
    prop1_kernel<<<NB, 256, 0, stream>>>(wb0, ptr, csr_row, dinv, ba3, wb1, N);

    // segment softmax + attention pooling
    segmax_kernel<<<NB, 256, 0, stream>>>(wb1, batch, segm, N);
    segexp_kernel<<<NB, 256, 0, stream>>>(wb1, batch, segm, wb0, segs, N);
    pooled_kernel<<<(N + 127) / 128, 128, 0, stream>>>(bufB, wb0, segs, batch, pooled, N);

    // final MLP
    mlp1_kernel<<<G, 128, 0, stream>>>(pooled, Wm1, bm1, hidden);
    mlp2_kernel<<<G, 256, 0, stream>>>(hidden, Wm2, bm2, out);
}

// Round 5
// 1249.964 us; speedup vs baseline: 1.9598x; 1.2688x over previous
//
#include <hip/hip_runtime.h>
#include <hip/hip_bf16.h>

struct f4 { float x, y, z, w; };
__device__ __forceinline__ f4 ld4(const float* p) { return *(const f4*)p; }
__device__ __forceinline__ void st4(float* p, f4 v) { *(f4*)p = v; }
__device__ __forceinline__ void acc4(f4& a, f4 b) { a.x += b.x; a.y += b.y; a.z += b.z; a.w += b.w; }

// ---------------- graph prep ----------------

__global__ void count_kernel(const int* __restrict__ col, int* __restrict__ cnt, int E) {
    int e = blockIdx.x * 256 + threadIdx.x;
    if (e < E) atomicAdd(&cnt[col[e]], 1);
}

// single-block exclusive scan of cnt[0..n) -> ptr[0..n]
__global__ void scan_kernel(const int* __restrict__ cnt, int* __restrict__ ptr, int n) {
    __shared__ int sums[1024];
    int t = threadIdx.x;
    int chunk = (n + 1023) / 1024;
    int lo = t * chunk;
    int hi = lo + chunk; if (hi > n) hi = n;
    int s = 0;
    for (int i = lo; i < hi; ++i) s += cnt[i];
    sums[t] = s;
    __syncthreads();
    for (int off = 1; off < 1024; off <<= 1) {
        int v = (t >= off) ? sums[t - off] : 0;
        __syncthreads();
        sums[t] += v;
        __syncthreads();
    }
    int run = (t == 0) ? 0 : sums[t - 1];
    for (int i = lo; i < hi; ++i) { ptr[i] = run; run += cnt[i]; }
    if (lo < n && hi == n) ptr[n] = run;
}

__global__ void dinv_fill_kernel(const int* __restrict__ cnt, const int* __restrict__ ptr,
                                 float* __restrict__ dinv, int* __restrict__ fillp, int n) {
    int i = blockIdx.x * 256 + threadIdx.x;
    if (i >= n) return;
    dinv[i] = rsqrtf((float)(cnt[i] + 1));   // deg includes self-loop, always >=1
    fillp[i] = ptr[i];
}

__global__ void fill_kernel(const int* __restrict__ row, const int* __restrict__ col,
                            int* __restrict__ fillp, int* __restrict__ csr_row, int E) {
    int e = blockIdx.x * 256 + threadIdx.x;
    if (e >= E) return;
    int c = col[e];
    int pos = atomicAdd(&fillp[c], 1);
    csr_row[pos] = row[e];
}

// ---------------- dense GEMM: C[n,FOUT] = (A[n,K] @ W[K,FOUT]) * scale[row] ----------------

template<int K, int FOUT>
__global__ __launch_bounds__(256) void gemm_kernel(const float* __restrict__ A,
                            const float* __restrict__ W, const float* __restrict__ scale,
                            float* __restrict__ C, int n) {
    constexpr int ROWS = 64;
    constexpr int NCG = FOUT / 4;       // column groups (4 cols each)
    constexpr int RG  = 256 / NCG;      // row groups
    constexpr int RPT = ROWS / RG;      // rows per thread
    __shared__ float As[ROWS * K];
    int t = threadIdx.x;
    int r0 = blockIdx.x * ROWS;
    for (int i = t; i < ROWS * K / 4; i += 256) {
        int idx = i * 4;
        int r = r0 + idx / K;
        f4 v;
        if (r < n) v = ld4(A + (size_t)r0 * K + idx);
        else { v.x = v.y = v.z = v.w = 0.f; }
        st4(As + idx, v);
    }
    __syncthreads();
    int cg = t % NCG, rg = t / NCG;
    int c = cg * 4, rb = rg * RPT;
    f4 acc[RPT];
#pragma unroll
    for (int i = 0; i < RPT; ++i) { acc[i].x = acc[i].y = acc[i].z = acc[i].w = 0.f; }
    for (int k = 0; k < K; k += 4) {
        f4 w0 = ld4(W + (size_t)(k + 0) * FOUT + c);
        f4 w1 = ld4(W + (size_t)(k + 1) * FOUT + c);
        f4 w2 = ld4(W + (size_t)(k + 2) * FOUT + c);
        f4 w3 = ld4(W + (size_t)(k + 3) * FOUT + c);
#pragma unroll
        for (int i = 0; i < RPT; ++i) {
            f4 a = ld4(As + (rb + i) * K + k);
            acc[i].x += a.x * w0.x + a.y * w1.x + a.z * w2.x + a.w * w3.x;
            acc[i].y += a.x * w0.y + a.y * w1.y + a.z * w2.y + a.w * w3.y;
            acc[i].z += a.x * w0.z + a.y * w1.z + a.z * w2.z + a.w * w3.z;
            acc[i].w += a.x * w0.w + a.y * w1.w + a.z * w2.w + a.w * w3.w;
        }
    }
#pragma unroll
    for (int i = 0; i < RPT; ++i) {
        int r = r0 + rb + i;
        if (r < n) {
            float s = scale[r];
            f4 v = acc[i];
            v.x *= s; v.y *= s; v.z *= s; v.w *= s;
            st4(C + (size_t)r * FOUT + c, v);
        }
    }
}

// K=32 -> 1 dot product per node, scaled by dinv
__global__ void dot32_kernel(const float* __restrict__ A, const float* __restrict__ W,
                             const float* __restrict__ dinv, float* __restrict__ out, int n) {
    int i = blockIdx.x * 256 + threadIdx.x;
    if (i >= n) return;
    float acc = 0.f;
#pragma unroll
    for (int k = 0; k < 32; k += 4) {
        f4 a = ld4(A + (size_t)i * 32 + k);
        f4 w = ld4(W + k);
        acc += a.x * w.x + a.y * w.y + a.z * w.z + a.w * w.w;
    }
    out[i] = acc * dinv[i];
}

// ---------------- propagate: out[v] = relu(dinv[v]*(sum_in hs[r] + hs[v]) + b) ----------------

template<int F>
__global__ __launch_bounds__(256) void prop_kernel(const float* __restrict__ Hs,
                            const int* __restrict__ ptr, const int* __restrict__ rows,
                            const float* __restrict__ dinv, const float* __restrict__ bias,
                            float* __restrict__ out, int n) {
    constexpr int L = F / 4;            // lanes per node
    constexpr int NPB = 256 / L;        // nodes per block
    int t = threadIdx.x;
    int q = t % L;
    int ln = t / L;
    int node = blockIdx.x * NPB + ln;
    if (node >= n) return;
    const int f4i = q * 4;
    f4 a0 = ld4(Hs + (size_t)node * F + f4i);   // self term (pre-scaled)
    f4 a1, a2, a3;
    a1.x=a1.y=a1.z=a1.w=0.f; a2=a1; a3=a1;
    int e0 = ptr[node], e1 = ptr[node + 1];
    int e = e0;
    for (; e + 4 <= e1; e += 4) {
        int r0 = rows[e], r1 = rows[e+1], r2 = rows[e+2], r3 = rows[e+3];
        acc4(a0, ld4(Hs + (size_t)r0 * F + f4i));
        acc4(a1, ld4(Hs + (size_t)r1 * F + f4i));
        acc4(a2, ld4(Hs + (size_t)r2 * F + f4i));
        acc4(a3, ld4(Hs + (size_t)r3 * F + f4i));
    }
    for (; e < e1; ++e) acc4(a0, ld4(Hs + (size_t)rows[e] * F + f4i));
    acc4(a0, a1); acc4(a2, a3); acc4(a0, a2);
    float dn = dinv[node];
    f4 b = ld4(bias + f4i);
    f4 v;
    v.x = a0.x * dn + b.x; v.y = a0.y * dn + b.y;
    v.z = a0.z * dn + b.z; v.w = a0.w * dn + b.w;
    v.x = v.x > 0.f ? v.x : 0.f; v.y = v.y > 0.f ? v.y : 0.f;
    v.z = v.z > 0.f ? v.z : 0.f; v.w = v.w > 0.f ? v.w : 0.f;
    st4(out + (size_t)node * F + f4i, v);
}

// F=1 variant
__global__ void prop1_kernel(const float* __restrict__ Hs, const int* __restrict__ ptr,
                             const int* __restrict__ rows, const float* __restrict__ dinv,
                             const float* __restrict__ bias, float* __restrict__ out, int n) {
    int node = blockIdx.x * 256 + threadIdx.x;
    if (node >= n) return;
    float a0 = Hs[node], a1 = 0.f, a2 = 0.f, a3 = 0.f;
    int e0 = ptr[node], e1 = ptr[node + 1];
    int e = e0;
    for (; e + 4 <= e1; e += 4) {
        a0 += Hs[rows[e]];
        a1 += Hs[rows[e+1]];
        a2 += Hs[rows[e+2]];
        a3 += Hs[rows[e+3]];
    }
    for (; e < e1; ++e) a0 += Hs[rows[e]];
    float v = (a0 + a1 + a2 + a3) * dinv[node] + bias[0];
    out[node] = v > 0.f ? v : 0.f;
}

// ---------------- segment softmax + pooling (sorted batch, no atomics) ----------------

// start[g] = lower_bound(batch, g); start[G] = n
__global__ void bounds_kernel(const int* __restrict__ batch, int* __restrict__ start,
                              int n, int g_cnt) {
    int g = blockIdx.x * 256 + threadIdx.x;
    if (g > g_cnt) return;
    if (g == g_cnt) { start[g] = n; return; }
    int lo = 0, hi = n;
    while (lo < hi) { int mid = (lo + hi) >> 1; if (batch[mid] < g) lo = mid + 1; else hi = mid; }
    start[g] = lo;
}

// one block per graph: max -> exp-sum -> weighted pooling, all in LDS
__global__ __launch_bounds__(256) void softpool_kernel(const float* __restrict__ x,
                              const float* __restrict__ w, const int* __restrict__ start,
                              float* __restrict__ pooled) {
    int g = blockIdx.x;
    int s = start[g], e = start[g + 1];
    int t = threadIdx.x;
    __shared__ float red[256];
    // phase 1: max
    float mx = -1e30f;
    for (int i = s + t; i < e; i += 256) mx = fmaxf(mx, w[i]);
    red[t] = mx; __syncthreads();
    for (int off = 128; off > 0; off >>= 1) {
        if (t < off) red[t] = fmaxf(red[t], red[t + off]);
        __syncthreads();
    }
    float m = (e > s) ? red[0] : 0.f;
    __syncthreads();
    // phase 2: sum of exp
    float sm = 0.f;
    for (int i = s + t; i < e; i += 256) sm += expf(w[i] - m);
    red[t] = sm; __syncthreads();
    for (int off = 128; off > 0; off >>= 1) {
        if (t < off) red[t] += red[t + off];
        __syncthreads();
    }
    float denom = red[0] + 1e-16f;
    __syncthreads();
    // phase 3: pooled[g,f] = sum_i x[i,f] * exp(w[i]-m)/denom ; 2 halves x 128 features
    int f = t & 127;
    int half = t >> 7;
    float acc = 0.f;
    for (int i = s + half; i < e; i += 2)
        acc += x[(size_t)i * 128 + f] * (expf(w[i] - m) / denom);
    red[t] = acc; __syncthreads();
    if (half == 0) pooled[g * 128 + f] = red[f] + red[128 + f];
}

// ---------------- final MLP ----------------

__global__ void mlp1_kernel(const float* __restrict__ pooled, const float* __restrict__ Wm1,
                            const float* __restrict__ bm1, float* __restrict__ hidden) {
    int g = blockIdx.x, j = threadIdx.x;   // 128 threads
    __shared__ float p[128];
    p[j] = pooled[g * 128 + j];
    __syncthreads();
    float acc = bm1[j];
    for (int k = 0; k < 128; ++k) acc += p[k] * Wm1[k * 128 + j];
    hidden[g * 128 + j] = acc > 0.f ? acc : 0.f;
}

__global__ void mlp2_kernel(const float* __restrict__ hidden, const float* __restrict__ Wm2,
                            const float* __restrict__ bm2, float* __restrict__ out) {
    int g = blockIdx.x, j = threadIdx.x;   // 256 threads
    __shared__ float h[128];
    if (j < 128) h[j] = hidden[g * 128 + j];
    __syncthreads();
    float acc = bm2[j];
    for (int k = 0; k < 128; ++k) acc += h[k] * Wm2[k * 256 + j];
    out[g * 256 + j] = acc;
}

// ---------------- launch ----------------

extern "C" void kernel_launch(void* const* d_in, const int* in_sizes, int n_in,
                              void* d_out, int out_size, void* d_ws, size_t ws_size,
                              hipStream_t stream) {
    const float* x    = (const float*)d_in[0];
    const int*   ei   = (const int*)d_in[1];
    const int*   batch= (const int*)d_in[2];
    const float* W1 = (const float*)d_in[3];  const float* b1 = (const float*)d_in[4];
    const float* W2 = (const float*)d_in[5];  const float* b2 = (const float*)d_in[6];
    const float* W3 = (const float*)d_in[7];  const float* b3 = (const float*)d_in[8];
    const float* Wa1= (const float*)d_in[9];  const float* ba1= (const float*)d_in[10];
    const float* Wa2= (const float*)d_in[11]; const float* ba2= (const float*)d_in[12];
    const float* Wa3= (const float*)d_in[13]; const float* ba3= (const float*)d_in[14];
    const float* Wm1= (const float*)d_in[15]; const float* bm1= (const float*)d_in[16];
    const float* Wm2= (const float*)d_in[17]; const float* bm2= (const float*)d_in[18];
    float* out = (float*)d_out;

    const int N = in_sizes[0] / 128;
    const int E = in_sizes[1] / 2;
    const int G = out_size / 256;

    const int* row = ei;        // edge_index[0]
    const int* col = ei + E;    // edge_index[1]

    // workspace layout (256B-aligned chunks)
    char* wp = (char*)d_ws;
    auto alloc = [&](size_t bytes) {
        void* p = wp;
        wp += (bytes + 255) & ~(size_t)255;
        return p;
    };
    int*   cnt     = (int*)alloc((size_t)N * 4);
    int*   ptr     = (int*)alloc((size_t)(N + 1) * 4);
    int*   fillp   = (int*)alloc((size_t)N * 4);
    int*   csr_row = (int*)alloc((size_t)E * 4);
    float* dinv    = (float*)alloc((size_t)N * 4);
    float* bufA    = (float*)alloc((size_t)N * 128 * 4);
    float* bufB    = (float*)alloc((size_t)N * 128 * 4);
    float* wb0     = (float*)alloc((size_t)N * 4);
    float* wb1     = (float*)alloc((size_t)N * 4);
    int*   gstart  = (int*)alloc((size_t)(G + 1) * 4);
    float* pooled  = (float*)alloc((size_t)G * 128 * 4);
    float* hidden  = (float*)alloc((size_t)G * 128 * 4);

    hipMemsetAsync(cnt, 0, (size_t)N * 4, stream);
    hipMemsetAsync(pooled, 0, (size_t)G * 128 * 4, stream);

    const int EB = (E + 255) / 256;
    const int NB = (N + 255) / 256;

    count_kernel<<<EB, 256, 0, stream>>>(col, cnt, E);
    scan_kernel<<<1, 1024, 0, stream>>>(cnt, ptr, N);
    dinv_fill_kernel<<<NB, 256, 0, stream>>>(cnt, ptr, dinv, fillp, N);
    fill_kernel<<<EB, 256, 0, stream>>>(row, col, fillp, csr_row, E);
    bounds_kernel<<<(G + 256) / 256, 256, 0, stream>>>(batch, gstart, N, G);

    const int GB64 = (N + 63) / 64;

    // GCN layer 1..3 (128 -> 128); GEMM writes hs = (A@W)*dinv[row]
    gemm_kernel<128,128><<<GB64, 256, 0, stream>>>(x,    W1, dinv, bufA, N);
    prop_kernel<128><<<(N + 7) / 8, 256, 0, stream>>>(bufA, ptr, csr_row, dinv, b1, bufB, N);
    gemm_kernel<128,128><<<GB64, 256, 0, stream>>>(bufB, W2, dinv, bufA, N);
    prop_kernel<128><<<(N + 7) / 8, 256, 0, stream>>>(bufA, ptr, csr_row, dinv, b2, bufB, N);
    gemm_kernel<128,128><<<GB64, 256, 0, stream>>>(bufB, W3, dinv, bufA, N);
    prop_kernel<128><<<(N + 7) / 8, 256, 0, stream>>>(bufA, ptr, csr_row, dinv, b3, bufB, N);
    // bufB = x3 [N,128]

    // attention branch
    float* a64_lin = bufA;                       // [N,64]
    float* a64     = bufA + (size_t)N * 64;      // [N,64]
    gemm_kernel<128,64><<<GB64, 256, 0, stream>>>(bufB, Wa1, dinv, a64_lin, N);
    prop_kernel<64><<<(N + 15) / 16, 256, 0, stream>>>(a64_lin, ptr, csr_row, dinv, ba1, a64, N);

    float* a32_lin = bufA;                       // [N,32] (a64_lin dead)
    float* a32     = bufA + (size_t)N * 32;      // [N,32]
    gemm_kernel<64,32><<<GB64, 256, 0, stream>>>(a64, Wa2, dinv, a32_lin, N);
    prop_kernel<32><<<(N + 31) / 32, 256, 0, stream>>>(a32_lin, ptr, csr_row, dinv, ba2, a32, N);

    dot32_kernel<<<NB, 256, 0, stream>>>(a32, Wa3, dinv, wb0, N);
    prop1_kernel<<<NB, 256, 0, stream>>>(wb0, ptr, csr_row, dinv, ba3, wb1, N);

    // fused segment softmax + attention pooling (no atomics; batch sorted)
    softpool_kernel<<<G, 256, 0, stream>>>(bufB, wb1, gstart, pooled);

    // final MLP
    mlp1_kernel<<<G, 128, 0, stream>>>(pooled, Wm1, bm1, hidden);
    mlp2_kernel<<<G, 256, 0, stream>>>(hidden, Wm2, bm2, out);
}

// Round 6
// 1102.925 us; speedup vs baseline: 2.2211x; 1.1333x over previous
//
#include <hip/hip_runtime.h>
#include <hip/hip_bf16.h>

struct f4 { float x, y, z, w; };
__device__ __forceinline__ f4 ld4(const float* p) { return *(const f4*)p; }
__device__ __forceinline__ void st4(float* p, f4 v) { *(f4*)p = v; }
__device__ __forceinline__ void acc4(f4& a, f4 b) { a.x += b.x; a.y += b.y; a.z += b.z; a.w += b.w; }

// ---------------- graph prep ----------------

__global__ void count_kernel(const int* __restrict__ col, int* __restrict__ cnt, int E) {
    int e = blockIdx.x * 256 + threadIdx.x;
    if (e < E) atomicAdd(&cnt[col[e]], 1);
}

// ---- device-wide exclusive scan of cnt[0..n) -> ptr[0..n], 3 passes ----

// pass 1: block b sums cnt[b*256 .. b*256+255] -> bsum[b]
__global__ void scan1_kernel(const int* __restrict__ cnt, int* __restrict__ bsum, int n) {
    __shared__ int red[256];
    int t = threadIdx.x;
    int i = blockIdx.x * 256 + t;
    red[t] = (i < n) ? cnt[i] : 0;
    __syncthreads();
    for (int off = 128; off > 0; off >>= 1) {
        if (t < off) red[t] += red[t + off];
        __syncthreads();
    }
    if (t == 0) bsum[blockIdx.x] = red[0];
}

// pass 2: single block exclusive-scans bsum[0..nb) in place (nb <= 1024)
__global__ void scan2_kernel(int* __restrict__ bsum, int nb) {
    __shared__ int s[1024];
    int t = threadIdx.x;
    int v = (t < nb) ? bsum[t] : 0;
    s[t] = v;
    __syncthreads();
    for (int off = 1; off < 1024; off <<= 1) {
        int u = (t >= off) ? s[t - off] : 0;
        __syncthreads();
        s[t] += u;
        __syncthreads();
    }
    if (t < nb) bsum[t] = s[t] - v;   // exclusive
}

// pass 3: in-block exclusive scan + block offset -> ptr; also writes ptr[n]
__global__ void scan3_kernel(const int* __restrict__ cnt, const int* __restrict__ bsum,
                             int* __restrict__ ptr, int n) {
    __shared__ int s[256];
    int t = threadIdx.x;
    int i = blockIdx.x * 256 + t;
    int v = (i < n) ? cnt[i] : 0;
    s[t] = v;
    __syncthreads();
    for (int off = 1; off < 256; off <<= 1) {
        int u = (t >= off) ? s[t - off] : 0;
        __syncthreads();
        s[t] += u;
        __syncthreads();
    }
    int excl = s[t] - v + bsum[blockIdx.x];
    if (i < n) ptr[i] = excl;
    if (i == n - 1) ptr[n] = excl + v;
}

__global__ void dinv_fill_kernel(const int* __restrict__ cnt, const int* __restrict__ ptr,
                                 float* __restrict__ dinv, int* __restrict__ fillp, int n) {
    int i = blockIdx.x * 256 + threadIdx.x;
    if (i >= n) return;
    dinv[i] = rsqrtf((float)(cnt[i] + 1));   // deg includes self-loop, always >=1
    fillp[i] = ptr[i];
}

__global__ void fill_kernel(const int* __restrict__ row, const int* __restrict__ col,
                            int* __restrict__ fillp, int* __restrict__ csr_row, int E) {
    int e = blockIdx.x * 256 + threadIdx.x;
    if (e >= E) return;
    int c = col[e];
    int pos = atomicAdd(&fillp[c], 1);
    csr_row[pos] = row[e];
}

// ---------------- dense GEMM: C[n,FOUT] = (A[n,K] @ W[K,FOUT]) * scale[row] ----------------

template<int K, int FOUT>
__global__ __launch_bounds__(256) void gemm_kernel(const float* __restrict__ A,
                            const float* __restrict__ W, const float* __restrict__ scale,
                            float* __restrict__ C, int n) {
    constexpr int ROWS = 64;
    constexpr int NCG = FOUT / 4;       // column groups (4 cols each)
    constexpr int RG  = 256 / NCG;      // row groups
    constexpr int RPT = ROWS / RG;      // rows per thread
    __shared__ float As[ROWS * K];
    int t = threadIdx.x;
    int r0 = blockIdx.x * ROWS;
    for (int i = t; i < ROWS * K / 4; i += 256) {
        int idx = i * 4;
        int r = r0 + idx / K;
        f4 v;
        if (r < n) v = ld4(A + (size_t)r0 * K + idx);
        else { v.x = v.y = v.z = v.w = 0.f; }
        st4(As + idx, v);
    }
    __syncthreads();
    int cg = t % NCG, rg = t / NCG;
    int c = cg * 4, rb = rg * RPT;
    f4 acc[RPT];
#pragma unroll
    for (int i = 0; i < RPT; ++i) { acc[i].x = acc[i].y = acc[i].z = acc[i].w = 0.f; }
    for (int k = 0; k < K; k += 4) {
        f4 w0 = ld4(W + (size_t)(k + 0) * FOUT + c);
        f4 w1 = ld4(W + (size_t)(k + 1) * FOUT + c);
        f4 w2 = ld4(W + (size_t)(k + 2) * FOUT + c);
        f4 w3 = ld4(W + (size_t)(k + 3) * FOUT + c);
#pragma unroll
        for (int i = 0; i < RPT; ++i) {
            f4 a = ld4(As + (rb + i) * K + k);
            acc[i].x += a.x * w0.x + a.y * w1.x + a.z * w2.x + a.w * w3.x;
            acc[i].y += a.x * w0.y + a.y * w1.y + a.z * w2.y + a.w * w3.y;
            acc[i].z += a.x * w0.z + a.y * w1.z + a.z * w2.z + a.w * w3.z;
            acc[i].w += a.x * w0.w + a.y * w1.w + a.z * w2.w + a.w * w3.w;
        }
    }
#pragma unroll
    for (int i = 0; i < RPT; ++i) {
        int r = r0 + rb + i;
        if (r < n) {
            float s = scale[r];
            f4 v = acc[i];
            v.x *= s; v.y *= s; v.z *= s; v.w *= s;
            st4(C + (size_t)r * FOUT + c, v);
        }
    }
}

// K=32 -> 1 dot product per node, scaled by dinv
__global__ void dot32_kernel(const float* __restrict__ A, const float* __restrict__ W,
                             const float* __restrict__ dinv, float* __restrict__ out, int n) {
    int i = blockIdx.x * 256 + threadIdx.x;
    if (i >= n) return;
    float acc = 0.f;
#pragma unroll
    for (int k = 0; k < 32; k += 4) {
        f4 a = ld4(A + (size_t)i * 32 + k);
        f4 w = ld4(W + k);
        acc += a.x * w.x + a.y * w.y + a.z * w.z + a.w * w.w;
    }
    out[i] = acc * dinv[i];
}

// ---------------- propagate: out[v] = relu(dinv[v]*(sum_in hs[r] + hs[v]) + b) ----------------

template<int F>
__global__ __launch_bounds__(256) void prop_kernel(const float* __restrict__ Hs,
                            const int* __restrict__ ptr, const int* __restrict__ rows,
                            const float* __restrict__ dinv, const float* __restrict__ bias,
                            float* __restrict__ out, int n) {
    constexpr int L = F / 4;            // lanes per node
    constexpr int NPB = 256 / L;        // nodes per block
    int t = threadIdx.x;
    int q = t % L;
    int ln = t / L;
    int node = blockIdx.x * NPB + ln;
    if (node >= n) return;
    const int f4i = q * 4;
    f4 a0 = ld4(Hs + (size_t)node * F + f4i);   // self term (pre-scaled)
    f4 a1, a2, a3;
    a1.x=a1.y=a1.z=a1.w=0.f; a2=a1; a3=a1;
    int e0 = ptr[node], e1 = ptr[node + 1];
    int e = e0;
    for (; e + 4 <= e1; e += 4) {
        int r0 = rows[e], r1 = rows[e+1], r2 = rows[e+2], r3 = rows[e+3];
        acc4(a0, ld4(Hs + (size_t)r0 * F + f4i));
        acc4(a1, ld4(Hs + (size_t)r1 * F + f4i));
        acc4(a2, ld4(Hs + (size_t)r2 * F + f4i));
        acc4(a3, ld4(Hs + (size_t)r3 * F + f4i));
    }
    for (; e < e1; ++e) acc4(a0, ld4(Hs + (size_t)rows[e] * F + f4i));
    acc4(a0, a1); acc4(a2, a3); acc4(a0, a2);
    float dn = dinv[node];
    f4 b = ld4(bias + f4i);
    f4 v;
    v.x = a0.x * dn + b.x; v.y = a0.y * dn + b.y;
    v.z = a0.z * dn + b.z; v.w = a0.w * dn + b.w;
    v.x = v.x > 0.f ? v.x : 0.f; v.y = v.y > 0.f ? v.y : 0.f;
    v.z = v.z > 0.f ? v.z : 0.f; v.w = v.w > 0.f ? v.w : 0.f;
    st4(out + (size_t)node * F + f4i, v);
}

// F=1 variant
__global__ void prop1_kernel(const float* __restrict__ Hs, const int* __restrict__ ptr,
                             const int* __restrict__ rows, const float* __restrict__ dinv,
                             const float* __restrict__ bias, float* __restrict__ out, int n) {
    int node = blockIdx.x * 256 + threadIdx.x;
    if (node >= n) return;
    float a0 = Hs[node], a1 = 0.f, a2 = 0.f, a3 = 0.f;
    int e0 = ptr[node], e1 = ptr[node + 1];
    int e = e0;
    for (; e + 4 <= e1; e += 4) {
        a0 += Hs[rows[e]];
        a1 += Hs[rows[e+1]];
        a2 += Hs[rows[e+2]];
        a3 += Hs[rows[e+3]];
    }
    for (; e < e1; ++e) a0 += Hs[rows[e]];
    float v = (a0 + a1 + a2 + a3) * dinv[node] + bias[0];
    out[node] = v > 0.f ? v : 0.f;
}

// ---------------- segment softmax + pooling (sorted batch, no atomics) ----------------

// start[g] = lower_bound(batch, g); start[G] = n
__global__ void bounds_kernel(const int* __restrict__ batch, int* __restrict__ start,
                              int n, int g_cnt) {
    int g = blockIdx.x * 256 + threadIdx.x;
    if (g > g_cnt) return;
    if (g == g_cnt) { start[g] = n; return; }
    int lo = 0, hi = n;
    while (lo < hi) { int mid = (lo + hi) >> 1; if (batch[mid] < g) lo = mid + 1; else hi = mid; }
    start[g] = lo;
}

// one block per graph: max -> exp-sum -> weighted pooling, all in LDS
__global__ __launch_bounds__(256) void softpool_kernel(const float* __restrict__ x,
                              const float* __restrict__ w, const int* __restrict__ start,
                              float* __restrict__ pooled) {
    int g = blockIdx.x;
    int s = start[g], e = start[g + 1];
    int t = threadIdx.x;
    __shared__ float red[256];
    // phase 1: max
    float mx = -1e30f;
    for (int i = s + t; i < e; i += 256) mx = fmaxf(mx, w[i]);
    red[t] = mx; __syncthreads();
    for (int off = 128; off > 0; off >>= 1) {
        if (t < off) red[t] = fmaxf(red[t], red[t + off]);
        __syncthreads();
    }
    float m = (e > s) ? red[0] : 0.f;
    __syncthreads();
    // phase 2: sum of exp
    float sm = 0.f;
    for (int i = s + t; i < e; i += 256) sm += expf(w[i] - m);
    red[t] = sm; __syncthreads();
    for (int off = 128; off > 0; off >>= 1) {
        if (t < off) red[t] += red[t + off];
        __syncthreads();
    }
    float denom = red[0] + 1e-16f;
    __syncthreads();
    // phase 3: pooled[g,f] = sum_i x[i,f] * exp(w[i]-m)/denom ; 2 halves x 128 features
    int f = t & 127;
    int half = t >> 7;
    float acc = 0.f;
    for (int i = s + half; i < e; i += 2)
        acc += x[(size_t)i * 128 + f] * (expf(w[i] - m) / denom);
    red[t] = acc; __syncthreads();
    if (half == 0) pooled[g * 128 + f] = red[f] + red[128 + f];
}

// ---------------- final MLP ----------------

__global__ void mlp1_kernel(const float* __restrict__ pooled, const float* __restrict__ Wm1,
                            const float* __restrict__ bm1, float* __restrict__ hidden) {
    int g = blockIdx.x, j = threadIdx.x;   // 128 threads
    __shared__ float p[128];
    p[j] = pooled[g * 128 + j];
    __syncthreads();
    float acc = bm1[j];
    for (int k = 0; k < 128; ++k) acc += p[k] * Wm1[k * 128 + j];
    hidden[g * 128 + j] = acc > 0.f ? acc : 0.f;
}

__global__ void mlp2_kernel(const float* __restrict__ hidden, const float* __restrict__ Wm2,
                            const float* __restrict__ bm2, float* __restrict__ out) {
    int g = blockIdx.x, j = threadIdx.x;   // 256 threads
    __shared__ float h[128];
    if (j < 128) h[j] = hidden[g * 128 + j];
    __syncthreads();
    float acc = bm2[j];
    for (int k = 0; k < 128; ++k) acc += h[k] * Wm2[k * 256 + j];
    out[g * 256 + j] = acc;
}

// ---------------- launch ----------------

extern "C" void kernel_launch(void* const* d_in, const int* in_sizes, int n_in,
                              void* d_out, int out_size, void* d_ws, size_t ws_size,
                              hipStream_t stream) {
    const float* x    = (const float*)d_in[0];
    const int*   ei   = (const int*)d_in[1];
    const int*   batch= (const int*)d_in[2];
    const float* W1 = (const float*)d_in[3];  const float* b1 = (const float*)d_in[4];
    const float* W2 = (const float*)d_in[5];  const float* b2 = (const float*)d_in[6];
    const float* W3 = (const float*)d_in[7];  const float* b3 = (const float*)d_in[8];
    const float* Wa1= (const float*)d_in[9];  const float* ba1= (const float*)d_in[10];
    const float* Wa2= (const float*)d_in[11]; const float* ba2= (const float*)d_in[12];
    const float* Wa3= (const float*)d_in[13]; const float* ba3= (const float*)d_in[14];
    const float* Wm1= (const float*)d_in[15]; const float* bm1= (const float*)d_in[16];
    const float* Wm2= (const float*)d_in[17]; const float* bm2= (const float*)d_in[18];
    float* out = (float*)d_out;

    const int N = in_sizes[0] / 128;
    const int E = in_sizes[1] / 2;
    const int G = out_size / 256;

    const int* row = ei;        // edge_index[0]
    const int* col = ei + E;    // edge_index[1]

    // workspace layout (256B-aligned chunks)
    char* wp = (char*)d_ws;
    auto alloc = [&](size_t bytes) {
        void* p = wp;
        wp += (bytes + 255) & ~(size_t)255;
        return p;
    };
    const int NB256 = (N + 255) / 256;   // scan blocks
    int*   cnt     = (int*)alloc((size_t)N * 4);
    int*   ptr     = (int*)alloc((size_t)(N + 1) * 4);
    int*   bsum    = (int*)alloc((size_t)NB256 * 4);
    int*   fillp   = (int*)alloc((size_t)N * 4);
    int*   csr_row = (int*)alloc((size_t)E * 4);
    float* dinv    = (float*)alloc((size_t)N * 4);
    float* bufA    = (float*)alloc((size_t)N * 128 * 4);
    float* bufB    = (float*)alloc((size_t)N * 128 * 4);
    float* wb0     = (float*)alloc((size_t)N * 4);
    float* wb1     = (float*)alloc((size_t)N * 4);
    int*   gstart  = (int*)alloc((size_t)(G + 1) * 4);
    float* pooled  = (float*)alloc((size_t)G * 128 * 4);
    float* hidden  = (float*)alloc((size_t)G * 128 * 4);

    hipMemsetAsync(cnt, 0, (size_t)N * 4, stream);

    const int EB = (E + 255) / 256;
    const int NB = NB256;

    count_kernel<<<EB, 256, 0, stream>>>(col, cnt, E);
    scan1_kernel<<<NB, 256, 0, stream>>>(cnt, bsum, N);
    scan2_kernel<<<1, 1024, 0, stream>>>(bsum, NB);
    scan3_kernel<<<NB, 256, 0, stream>>>(cnt, bsum, ptr, N);
    dinv_fill_kernel<<<NB, 256, 0, stream>>>(cnt, ptr, dinv, fillp, N);
    fill_kernel<<<EB, 256, 0, stream>>>(row, col, fillp, csr_row, E);
    bounds_kernel<<<(G + 256) / 256, 256, 0, stream>>>(batch, gstart, N, G);

    const int GB64 = (N + 63) / 64;

    // GCN layer 1..3 (128 -> 128); GEMM writes hs = (A@W)*dinv[row]
    gemm_kernel<128,128><<<GB64, 256, 0, stream>>>(x,    W1, dinv, bufA, N);
    prop_kernel<128><<<(N + 7) / 8, 256, 0, stream>>>(bufA, ptr, csr_row, dinv, b1, bufB, N);
    gemm_kernel<128,128><<<GB64, 256, 0, stream>>>(bufB, W2, dinv, bufA, N);
    prop_kernel<128><<<(N + 7) / 8, 256, 0, stream>>>(bufA, ptr, csr_row, dinv, b2, bufB, N);
    gemm_kernel<128,128><<<GB64, 256, 0, stream>>>(bufB, W3, dinv, bufA, N);
    prop_kernel<128><<<(N + 7) / 8, 256, 0, stream>>>(bufA, ptr, csr_row, dinv, b3, bufB, N);
    // bufB = x3 [N,128]

    // attention branch
    float* a64_lin = bufA;                       // [N,64]
    float* a64     = bufA + (size_t)N * 64;      // [N,64]
    gemm_kernel<128,64><<<GB64, 256, 0, stream>>>(bufB, Wa1, dinv, a64_lin, N);
    prop_kernel<64><<<(N + 15) / 16, 256, 0, stream>>>(a64_lin, ptr, csr_row, dinv, ba1, a64, N);

    float* a32_lin = bufA;                       // [N,32] (a64_lin dead)
    float* a32     = bufA + (size_t)N * 32;      // [N,32]
    gemm_kernel<64,32><<<GB64, 256, 0, stream>>>(a64, Wa2, dinv, a32_lin, N);
    prop_kernel<32><<<(N + 31) / 32, 256, 0, stream>>>(a32_lin, ptr, csr_row, dinv, ba2, a32, N);

    dot32_kernel<<<NB, 256, 0, stream>>>(a32, Wa3, dinv, wb0, N);
    prop1_kernel<<<NB, 256, 0, stream>>>(wb0, ptr, csr_row, dinv, ba3, wb1, N);

    // fused segment softmax + attention pooling (no atomics; batch sorted)
    softpool_kernel<<<G, 256, 0, stream>>>(bufB, wb1, gstart, pooled);

    // final MLP
    mlp1_kernel<<<G, 128, 0, stream>>>(pooled, Wm1, bm1, hidden);
    mlp2_kernel<<<G, 256, 0, stream>>>(hidden, Wm2, bm2, out);
}